// Round 8
// baseline (45.199 us; speedup 1.0000x reference)
//
#include <hip/hip_runtime.h>
#include <math.h>

#define NN 1024
#define DD 64
#define HH 256
#define TEMP_INV 10.0f
#define KCH 64
#define NCH 4

// Identity used: relu(z)*w2 = u + sign(w2)*|u|,  u = 0.5*w2*z,
// z = yp_i + xp_j + b1  ->  u = y''_i + x''_j  with y''=0.5*w2*yp,
// x''=0.5*w2*(xp+b1).  scores_raw[i][j] = A_i + B_j + sum_k s_k*|y''+x''|,
// A_i = sum_k y'', B_j = sum_k x''.  k is permuted so sign(w2) is sorted:
// s_k = +1 for k < kpos, -1 after (one straddle chunk fixed up).
//
// ws layout (floats):
//   y2   [NN][HH] : y'' (k-permuted, row-major)       1 MB
//   x2T  [HH][NN] : x'' (k-permuted, k-major)         1 MB
//   A[NN], B[NN], posr[NN]
//   pmax [16][NN], psum [16][NN]
//   kposD (int)

__global__ __launch_bounds__(256)
void k1_proj(const float* __restrict__ x, const float* __restrict__ y,
             const float* __restrict__ W1, const float* __restrict__ b1,
             const float* __restrict__ w2,
             float* __restrict__ y2, float* __restrict__ x2T,
             float* __restrict__ Aarr, float* __restrict__ Barr,
             float* __restrict__ posr, int* __restrict__ kposD)
{
    __shared__ float red[6][256];
    __shared__ unsigned int cnts[4];
    const int tid = threadIdx.x;        // h index 0..255
    const int i0 = blockIdx.x * 2;
    float ax0 = 0.f, ax1 = 0.f, ay0 = 0.f, ay1 = 0.f;
    #pragma unroll 8
    for (int kk = 0; kk < DD; ++kk) {
        const float wx = W1[kk * HH + tid];
        const float wy = W1[(DD + kk) * HH + tid];
        ax0 = fmaf(x[i0 * DD + kk],       wx, ax0);
        ax1 = fmaf(x[(i0 + 1) * DD + kk], wx, ax1);
        ay0 = fmaf(y[i0 * DD + kk],       wy, ay0);
        ay1 = fmaf(y[(i0 + 1) * DD + kk], wy, ay1);
    }
    const float w2t = w2[tid], b1t = b1[tid];
    const float xb0 = ax0 + b1t, xb1 = ax1 + b1t;
    const float hw  = 0.5f * w2t;
    const float xf0 = hw * xb0, xf1 = hw * xb1;
    const float yf0 = hw * ay0, yf1 = hw * ay1;
    const float p0 = fmaxf(ay0 + xb0, 0.f) * w2t;   // diagonal term, row i0
    const float p1 = fmaxf(ay1 + xb1, 0.f) * w2t;   // row i0+1

    // deterministic sign-partition permutation of k (same in every block)
    const int lane = tid & 63, wv = tid >> 6;
    const bool nonneg = (w2t >= 0.f);
    const unsigned long long bal = __ballot(nonneg);
    const int before = __popcll(bal & ((1ull << lane) - 1ull));
    if (lane == 0) cnts[wv] = (unsigned int)__popcll(bal);
    __syncthreads();
    const int kpos = (int)(cnts[0] + cnts[1] + cnts[2] + cnts[3]);
    int posbase = 0;
    for (int u = 0; u < wv; ++u) posbase += (int)cnts[u];
    const int rank = nonneg ? (posbase + before)
                            : (kpos + wv * 64 - posbase + lane - before);

    y2[(i0)     * HH + rank] = yf0;
    y2[(i0 + 1) * HH + rank] = yf1;
    *(float2*)&x2T[rank * NN + i0] = make_float2(xf0, xf1);
    if (blockIdx.x == 0 && tid == 0) kposD[0] = kpos;

    red[0][tid] = yf0; red[1][tid] = yf1;
    red[2][tid] = xf0; red[3][tid] = xf1;
    red[4][tid] = p0;  red[5][tid] = p1;
    __syncthreads();
    for (int s = 128; s > 0; s >>= 1) {
        if (tid < s) {
            #pragma unroll
            for (int j = 0; j < 6; ++j) red[j][tid] += red[j][tid + s];
        }
        __syncthreads();
    }
    if (tid == 0) {
        Aarr[i0] = red[0][0]; Aarr[i0 + 1] = red[1][0];
        Barr[i0] = red[2][0]; Barr[i0 + 1] = red[3][0];
        posr[i0] = red[4][0]; posr[i0 + 1] = red[5][0];
    }
}

// 64x64 tile, full K=256. 512 thr, P4xQ2 per thread. Only x'' lives in LDS
// (b64 reads); y'' comes from global (broadcast float4, L2-hot); w2 is gone.
// Inner: 2 VALU ops per output per kk (add + fma with |.| src modifier).
__global__ __launch_bounds__(512)
void k2_scores(const float* __restrict__ x2T, const float* __restrict__ y2,
               const float* __restrict__ Aarr, const float* __restrict__ Barr,
               const float* __restrict__ b2, const int* __restrict__ kposD,
               float* __restrict__ pmax, float* __restrict__ psum)
{
    __shared__ float xs[2][KCH][64];   // 32 KB
    const int t  = threadIdx.x;
    const int bj = blockIdx.x, bi = blockIdx.y;
    const int i0 = bi * 64, j0 = bj * 64;
    const int rr = t >> 5;   // 0..15 -> rows rbase..+3
    const int cc = t & 31;   // 0..31 -> cols j0+2cc, +1
    const int kpos = kposD[0];
    const int rbase = i0 + rr * 4;

    float acc[4][2];
    #pragma unroll
    for (int p = 0; p < 4; ++p) { acc[p][0] = 0.f; acc[p][1] = 0.f; }

    #define STG(c, buf)                                                        \
    {                                                                          \
        const int k0s = (c) * KCH;                                             \
        _Pragma("unroll")                                                      \
        for (int h = 0; h < 2; ++h) {                                          \
            const int f = t + h * 512;                                         \
            const int r = f >> 4, c4 = (f & 15) * 4;                           \
            *(float4*)&xs[buf][r][c4] =                                        \
                *(const float4*)&x2T[(k0s + r) * NN + j0 + c4];                \
        }                                                                      \
    }

    STG(0, 0);
    __syncthreads();
    for (int c = 0; c < NCH; ++c) {
        if (c + 1 < NCH) STG(c + 1, (c + 1) & 1);
        const int cur = c & 1;
        const int k0 = c * KCH;
        const int mm = kpos - k0;                  // uniform
        const float sgn = (mm > 0) ? 1.f : -1.f;
        #pragma unroll 4
        for (int g = 0; g < 16; ++g) {
            const int kb = k0 + g * 4;
            float4 yv[4];
            #pragma unroll
            for (int p = 0; p < 4; ++p)
                yv[p] = *(const float4*)&y2[(rbase + p) * HH + kb];
            #pragma unroll
            for (int e = 0; e < 4; ++e) {
                const float2 xv = *(const float2*)&xs[cur][g * 4 + e][cc * 2];
                #pragma unroll
                for (int p = 0; p < 4; ++p) {
                    const float yp_ = (e == 0) ? yv[p].x : (e == 1) ? yv[p].y
                                    : (e == 2) ? yv[p].z : yv[p].w;
                    acc[p][0] = fmaf(sgn, fabsf(yp_ + xv.x), acc[p][0]);
                    acc[p][1] = fmaf(sgn, fabsf(yp_ + xv.y), acc[p][1]);
                }
            }
        }
        if (mm > 0 && mm < KCH) {                  // straddle chunk fixup
            for (int kk = mm; kk < KCH; ++kk) {
                const float2 xv = *(const float2*)&xs[cur][kk][cc * 2];
                #pragma unroll
                for (int p = 0; p < 4; ++p) {
                    const float yv1 = y2[(rbase + p) * HH + k0 + kk];
                    acc[p][0] = fmaf(-2.f, fabsf(yv1 + xv.x), acc[p][0]);
                    acc[p][1] = fmaf(-2.f, fabsf(yv1 + xv.y), acc[p][1]);
                }
            }
        }
        __syncthreads();
    }
    #undef STG

    // epilogue: scores + per-row partial LSE over this block's 64 cols
    const float bb = b2[0];
    const float Bv0 = Barr[j0 + cc * 2], Bv1 = Barr[j0 + cc * 2 + 1];
    float m[4], e[4];
    #pragma unroll
    for (int p = 0; p < 4; ++p) {
        const float Av = Aarr[rbase + p];
        const float s0 = (Av + Bv0 + acc[p][0] + bb) * TEMP_INV;
        const float s1 = (Av + Bv1 + acc[p][1] + bb) * TEMP_INV;
        m[p] = fmaxf(s0, s1);
        e[p] = __expf(s0 - m[p]) + __expf(s1 - m[p]);
    }
    #pragma unroll
    for (int mk = 16; mk >= 1; mk >>= 1) {
        #pragma unroll
        for (int p = 0; p < 4; ++p) {
            const float mo = __shfl_xor(m[p], mk);
            const float eo = __shfl_xor(e[p], mk);
            const float mn = fmaxf(m[p], mo);
            e[p] = e[p] * __expf(m[p] - mn) + eo * __expf(mo - mn);
            m[p] = mn;
        }
    }
    if (cc == 0) {
        #pragma unroll
        for (int p = 0; p < 4; ++p) {
            pmax[bj * NN + rbase + p] = m[p];
            psum[bj * NN + rbase + p] = e[p];
        }
    }
}

__global__ __launch_bounds__(1024)
void k3_final(const float* __restrict__ pmax, const float* __restrict__ psum,
              const float* __restrict__ posr, const float* __restrict__ b2,
              float* __restrict__ out)
{
    __shared__ float2 red[1024];
    const int tid = threadIdx.x;      // row
    const float bb = b2[0];
    float M = pmax[tid], E = psum[tid];
    #pragma unroll
    for (int jc = 1; jc < 16; ++jc) {
        const float Mo = pmax[jc * NN + tid];
        const float Eo = psum[jc * NN + tid];
        const float Mn = fmaxf(M, Mo);
        E = E * __expf(M - Mn) + Eo * __expf(Mo - Mn);
        M = Mn;
    }
    const float pos_s = (posr[tid] + bb) * TEMP_INV;
    red[tid] = make_float2(M + logf(E), pos_s);
    __syncthreads();
    for (int s = 512; s > 0; s >>= 1) {
        if (tid < s) {
            const float2 o = red[tid + s];
            float2 m2 = red[tid];
            m2.x += o.x; m2.y += o.y;
            red[tid] = m2;
        }
        __syncthreads();
    }
    if (tid == 0)
        out[0] = red[0].x / (float)NN - logf((float)NN) - red[0].y / (float)NN;
}

extern "C" void kernel_launch(void* const* d_in, const int* in_sizes, int n_in,
                              void* d_out, int out_size, void* d_ws, size_t ws_size,
                              hipStream_t stream)
{
    const float* x  = (const float*)d_in[0];
    const float* y  = (const float*)d_in[1];
    const float* W1 = (const float*)d_in[2];
    const float* b1 = (const float*)d_in[3];
    const float* w2 = (const float*)d_in[4];
    const float* b2 = (const float*)d_in[5];
    float* out = (float*)d_out;

    float* ws   = (float*)d_ws;
    float* y2   = ws;                 // NN*HH
    float* x2T  = y2 + NN * HH;       // HH*NN
    float* Aarr = x2T + HH * NN;      // NN
    float* Barr = Aarr + NN;          // NN
    float* posr = Barr + NN;          // NN
    float* pmax = posr + NN;          // 16*NN
    float* psum = pmax + 16 * NN;     // 16*NN
    int*  kposD = (int*)(psum + 16 * NN);

    hipLaunchKernelGGL(k1_proj, dim3(NN / 2), dim3(256), 0, stream,
                       x, y, W1, b1, w2, y2, x2T, Aarr, Barr, posr, kposD);
    hipLaunchKernelGGL(k2_scores, dim3(16, 16), dim3(512), 0, stream,
                       x2T, y2, Aarr, Barr, b2, kposD, pmax, psum);
    hipLaunchKernelGGL(k3_final, dim3(1), dim3(1024), 0, stream,
                       pmax, psum, posr, b2, out);
}